// Round 1
// baseline (29453.186 us; speedup 1.0000x reference)
//
#include <hip/hip_runtime.h>
#include <math.h>

// Problem dims (fixed)
//  B=64, T=512, I=512, H=1024, O=512
#define NBLK 256

// ---------------------------------------------------------------------------
// Grid barrier: monotonic counter, stale-read safe (counter only grows, so a
// stale load can only cause extra spinning, never early exit).
// ---------------------------------------------------------------------------
__device__ __forceinline__ void grid_bar(unsigned* cnt) {
  __syncthreads();
  if (threadIdx.x == 0) {
    __threadfence();  // publish this block's global writes (device scope)
    unsigned arrive = __hip_atomic_fetch_add(cnt, 1u, __ATOMIC_RELEASE,
                                             __HIP_MEMORY_SCOPE_AGENT);
    unsigned target = arrive / NBLK * NBLK + NBLK;
    while (__hip_atomic_load(cnt, __ATOMIC_ACQUIRE,
                             __HIP_MEMORY_SCOPE_AGENT) < target) {
      __builtin_amdgcn_s_sleep(2);
    }
    __threadfence();  // acquire side belt-and-braces
  }
  __syncthreads();
}

// ---------------------------------------------------------------------------
// GEMM1: xp[m][n] = inputs[m][k] * W_xh[k][n];  M=32768, K=512, N=1024
// BM=128, BN=128, BK=8, 256 threads, 8x8 per thread.
// ---------------------------------------------------------------------------
__global__ __launch_bounds__(256) void gemm_xh(const float* __restrict__ A,
                                               const float* __restrict__ Bw,
                                               float* __restrict__ C) {
  const int M_K = 512;   // A row stride
  const int N = 1024;
  __shared__ float As[8][128];
  __shared__ float Bs[8][128];
  const int m0 = blockIdx.y * 128;
  const int n0 = blockIdx.x * 128;
  const int tid = threadIdx.x;
  const int tm = tid >> 4, tn = tid & 15;
  float acc[8][8] = {};

  const int arow = tid >> 1;
  const int akq  = (tid & 1) * 4;
  const int brow = tid >> 5;
  const int bcol = (tid & 31) * 4;

  for (int k0 = 0; k0 < 512; k0 += 8) {
    float4 av = *(const float4*)&A[(size_t)(m0 + arow) * M_K + k0 + akq];
    float4 bv = *(const float4*)&Bw[(size_t)(k0 + brow) * N + n0 + bcol];
    __syncthreads();
    As[akq + 0][arow] = av.x; As[akq + 1][arow] = av.y;
    As[akq + 2][arow] = av.z; As[akq + 3][arow] = av.w;
    *(float4*)&Bs[brow][bcol] = bv;
    __syncthreads();
#pragma unroll
    for (int kk = 0; kk < 8; ++kk) {
      float a[8], b[8];
      *(float4*)&a[0] = *(const float4*)&As[kk][tm * 8];
      *(float4*)&a[4] = *(const float4*)&As[kk][tm * 8 + 4];
      *(float4*)&b[0] = *(const float4*)&Bs[kk][tn * 8];
      *(float4*)&b[4] = *(const float4*)&Bs[kk][tn * 8 + 4];
#pragma unroll
      for (int i = 0; i < 8; ++i)
#pragma unroll
        for (int j = 0; j < 8; ++j) acc[i][j] = fmaf(a[i], b[j], acc[i][j]);
    }
  }
#pragma unroll
  for (int i = 0; i < 8; ++i) {
    float4* crow = (float4*)&C[(size_t)(m0 + tm * 8 + i) * N + n0 + tn * 8];
    crow[0] = make_float4(acc[i][0], acc[i][1], acc[i][2], acc[i][3]);
    crow[1] = make_float4(acc[i][4], acc[i][5], acc[i][6], acc[i][7]);
  }
}

// ---------------------------------------------------------------------------
// Persistent cooperative scan kernel.
// 256 blocks: bid -> (kg in 8, jg in 16, bg in 2).
// Each block: W_hh slice [k0..k0+128) x [j0..j0+64) resident in LDS.
// Per step t:
//   phase A: stage h_{t-1}[b0..b0+32)[k-slice] (transposed) to LDS,
//            compute partial P[kg][b][j] = sum_k h*W;  barrier.
//   phase B: each thread owns one (b,j): h_t = tanh(xp_t + b_h + sum_kg P);
//            write h_t to its slot (xp slot t-1; t==0 -> h0buf); barrier.
// ---------------------------------------------------------------------------
__global__ __launch_bounds__(256) void rnn_scan(float* __restrict__ xp,
                                                const float* __restrict__ init_h,
                                                const float* __restrict__ Whh,
                                                const float* __restrict__ bh,
                                                float* __restrict__ h0buf,
                                                float* __restrict__ P,
                                                float* __restrict__ outtail,
                                                unsigned* __restrict__ bar) {
  __shared__ float Wl[128][64];   // 32 KB
  __shared__ float ht[128][34];   // 17 KB (pad 34 keeps b64 align + spreads banks)
  const int tid = threadIdx.x;
  const int bid = blockIdx.x;
  const int kg = bid & 7;
  const int jg = (bid >> 3) & 15;
  const int bg = bid >> 7;
  const int k0 = kg << 7, j0 = jg << 6, b0 = bg << 5;

  {  // stage W_hh slice (once)
    const int jr = (tid & 15) * 4;
    const int kr = tid >> 4;
#pragma unroll
    for (int p = 0; p < 8; ++p) {
      const int kk = kr + p * 16;
      *(float4*)&Wl[kk][jr] =
          *(const float4*)&Whh[(size_t)(k0 + kk) * 1024 + j0 + jr];
    }
  }

  const int tb = tid >> 4;        // 0..15 : b pair
  const int tj = tid & 15;        // 0..15 : j quad
  const int sb = tid >> 5;        // 0..7  : staging row
  const int sk = (tid & 31) * 4;  // staging k quad
  const int e  = (bid << 8) + tid;  // phase-B element 0..65535
  const int eb = e >> 10;
  const int ej = e & 1023;
  const float bhj = bh[ej];

  for (int t = 0; t < 512; ++t) {
    // ---- phase A ----
    const float* hs;
    size_t rstride;
    if (t == 0)      { hs = init_h;                      rstride = 1024; }
    else if (t == 1) { hs = h0buf;                       rstride = 1024; }
    else             { hs = xp + (size_t)(t - 2) * 1024; rstride = 512 * 1024; }
    __syncthreads();  // previous inner loop done before ht overwrite (covers Wl stage on t=0)
#pragma unroll
    for (int p = 0; p < 4; ++p) {
      const int bb = sb + (p << 3);
      float4 hv = *(const float4*)&hs[(size_t)(b0 + bb) * rstride + k0 + sk];
      ht[sk + 0][bb] = hv.x; ht[sk + 1][bb] = hv.y;
      ht[sk + 2][bb] = hv.z; ht[sk + 3][bb] = hv.w;
    }
    __syncthreads();

    float4 acc0 = {0.f, 0.f, 0.f, 0.f};
    float4 acc1 = {0.f, 0.f, 0.f, 0.f};
#pragma unroll 8
    for (int kk = 0; kk < 128; ++kk) {
      const float2 hb = *(const float2*)&ht[kk][tb * 2];
      const float4 w  = *(const float4*)&Wl[kk][tj * 4];
      acc0.x = fmaf(hb.x, w.x, acc0.x); acc0.y = fmaf(hb.x, w.y, acc0.y);
      acc0.z = fmaf(hb.x, w.z, acc0.z); acc0.w = fmaf(hb.x, w.w, acc0.w);
      acc1.x = fmaf(hb.y, w.x, acc1.x); acc1.y = fmaf(hb.y, w.y, acc1.y);
      acc1.z = fmaf(hb.y, w.z, acc1.z); acc1.w = fmaf(hb.y, w.w, acc1.w);
    }
    {
      const size_t base = ((size_t)(kg * 64) + b0 + tb * 2) * 1024 + j0 + tj * 4;
      *(float4*)&P[base]        = acc0;
      *(float4*)&P[base + 1024] = acc1;
    }
    grid_bar(bar);

    // ---- phase B ----
    float v = xp[((size_t)eb * 512 + t) * 1024 + ej] + bhj;
    float ps[8];
#pragma unroll
    for (int g = 0; g < 8; ++g)
      ps[g] = P[((size_t)(g * 64) + eb) * 1024 + ej];
#pragma unroll
    for (int g = 0; g < 8; ++g) v += ps[g];
    const float h = tanhf(v);
    if (t == 0) h0buf[e] = h;
    else        xp[((size_t)eb * 512 + (t - 1)) * 1024 + ej] = h;
    if (t == 511) outtail[e] = h;
    grid_bar(bar);
  }
}

// ---------------------------------------------------------------------------
// GEMM3: out[b,t,:] = h_t @ W_hy + b_y;  M=32768 rows (b*512+t), K=1024, N=512
// h_t lives at xp slot (t-1) for t>=1, h0buf for t==0.
// ---------------------------------------------------------------------------
__global__ __launch_bounds__(256) void gemm_hy(const float* __restrict__ hall,
                                               const float* __restrict__ h0,
                                               const float* __restrict__ Wm,
                                               const float* __restrict__ by,
                                               float* __restrict__ out) {
  const int N = 512;
  __shared__ float As[8][128];
  __shared__ float Bs[8][128];
  const int m0 = blockIdx.y * 128;
  const int n0 = blockIdx.x * 128;
  const int tid = threadIdx.x;
  const int tm = tid >> 4, tn = tid & 15;
  float acc[8][8] = {};

  const int arow = tid >> 1;
  const int akq  = (tid & 1) * 4;
  const int brow = tid >> 5;
  const int bcol = (tid & 31) * 4;

  const int row = m0 + arow;
  const int bb = row >> 9;
  const int tt = row & 511;
  const float* abase = (tt == 0)
      ? (h0 + (size_t)bb * 1024)
      : (hall + ((size_t)bb * 512 + (tt - 1)) * 1024);

  for (int k0 = 0; k0 < 1024; k0 += 8) {
    float4 av = *(const float4*)&abase[k0 + akq];
    float4 bv = *(const float4*)&Wm[(size_t)(k0 + brow) * N + n0 + bcol];
    __syncthreads();
    As[akq + 0][arow] = av.x; As[akq + 1][arow] = av.y;
    As[akq + 2][arow] = av.z; As[akq + 3][arow] = av.w;
    *(float4*)&Bs[brow][bcol] = bv;
    __syncthreads();
#pragma unroll
    for (int kk = 0; kk < 8; ++kk) {
      float a[8], b[8];
      *(float4*)&a[0] = *(const float4*)&As[kk][tm * 8];
      *(float4*)&a[4] = *(const float4*)&As[kk][tm * 8 + 4];
      *(float4*)&b[0] = *(const float4*)&Bs[kk][tn * 8];
      *(float4*)&b[4] = *(const float4*)&Bs[kk][tn * 8 + 4];
#pragma unroll
      for (int i = 0; i < 8; ++i)
#pragma unroll
        for (int j = 0; j < 8; ++j) acc[i][j] = fmaf(a[i], b[j], acc[i][j]);
    }
  }
  float byv[8];
  *(float4*)&byv[0] = *(const float4*)&by[n0 + tn * 8];
  *(float4*)&byv[4] = *(const float4*)&by[n0 + tn * 8 + 4];
#pragma unroll
  for (int i = 0; i < 8; ++i) {
    const int r = m0 + tm * 8 + i;
    float4* crow = (float4*)&out[(size_t)r * N + n0 + tn * 8];
    crow[0] = make_float4(acc[i][0] + byv[0], acc[i][1] + byv[1],
                          acc[i][2] + byv[2], acc[i][3] + byv[3]);
    crow[1] = make_float4(acc[i][4] + byv[4], acc[i][5] + byv[5],
                          acc[i][6] + byv[6], acc[i][7] + byv[7]);
  }
}

// ---------------------------------------------------------------------------
extern "C" void kernel_launch(void* const* d_in, const int* in_sizes, int n_in,
                              void* d_out, int out_size, void* d_ws, size_t ws_size,
                              hipStream_t stream) {
  const float* inputs = (const float*)d_in[0];  // [64][512][512]
  const float* init_h = (const float*)d_in[1];  // [64][1024]
  const float* W_xh   = (const float*)d_in[2];  // [512][1024]
  const float* W_hh   = (const float*)d_in[3];  // [1024][1024]
  const float* W_hy   = (const float*)d_in[4];  // [1024][512]
  const float* b_h    = (const float*)d_in[5];  // [1024]
  const float* b_y    = (const float*)d_in[6];  // [512]
  float* out = (float*)d_out;                   // [64][512][512] ++ [64][1024]

  // Workspace layout (floats):
  //   xp    : 64*512*1024  (x_proj, later overwritten in place by h_t at slot t-1)
  //   h0buf : 64*1024      (h_0)
  //   P     : 8*64*1024    (K-split partials)
  //   bar   : barrier counter
  float* xp    = (float*)d_ws;
  float* h0buf = xp + (size_t)64 * 512 * 1024;
  float* P     = h0buf + (size_t)64 * 1024;
  unsigned* bar = (unsigned*)(P + (size_t)8 * 64 * 1024);

  hipMemsetAsync(bar, 0, 256, stream);

  gemm_xh<<<dim3(8, 256), 256, 0, stream>>>(inputs, W_xh, xp);

  float* outtail = out + (size_t)64 * 512 * 512;
  void* args[] = { (void*)&xp, (void*)&init_h, (void*)&W_hh, (void*)&b_h,
                   (void*)&h0buf, (void*)&P, (void*)&outtail, (void*)&bar };
  hipLaunchCooperativeKernel((const void*)rnn_scan, dim3(NBLK), dim3(256),
                             args, 0, stream);

  gemm_hy<<<dim3(4, 256), 256, 0, stream>>>(xp, h0buf, W_hy, b_y, out);
}

// Round 3
// 20846.489 us; speedup vs baseline: 1.4129x; 1.4129x over previous
//
#include <hip/hip_runtime.h>
#include <math.h>

// Problem dims (fixed)
//  B=64, T=512, I=512, H=1024, O=512
#define NBLK 256

// ---------------------------------------------------------------------------
// Contention-free grid barrier.
//  - each block publishes its own flag word (no RMW, no shared-line atomics)
//  - release: one agent-release fence by thread 0 only
//  - poll: RELAXED agent loads (no per-iteration L2 invalidate!); thread i
//    watches flags[i]  (requires blockDim.x == NBLK == 256)
//  - one acquire fence after the whole block has observed all flags
//  - targets increase monotonically; stale reads can only over-spin.
// ---------------------------------------------------------------------------
__device__ __forceinline__ void grid_bar(unsigned* flags, unsigned target) {
  __syncthreads();  // all block stores issued before publish
  if (threadIdx.x == 0) {
    __builtin_amdgcn_fence(__ATOMIC_RELEASE, "agent");  // publish to L2/LLC
    __hip_atomic_store(&flags[blockIdx.x], target, __ATOMIC_RELAXED,
                       __HIP_MEMORY_SCOPE_AGENT);
  }
  while (__hip_atomic_load(&flags[threadIdx.x], __ATOMIC_RELAXED,
                           __HIP_MEMORY_SCOPE_AGENT) < target) {
    __builtin_amdgcn_s_sleep(2);
  }
  __syncthreads();  // whole block has observed all 256 flags
  __builtin_amdgcn_fence(__ATOMIC_ACQUIRE, "agent");  // inv stale lines, once
}

// ---------------------------------------------------------------------------
// GEMM1: xp[m][n] = inputs[m][k] * W_xh[k][n];  M=32768, K=512, N=1024
// ---------------------------------------------------------------------------
__global__ __launch_bounds__(256) void gemm_xh(const float* __restrict__ A,
                                               const float* __restrict__ Bw,
                                               float* __restrict__ C) {
  const int M_K = 512;
  const int N = 1024;
  __shared__ float As[8][128];
  __shared__ float Bs[8][128];
  const int m0 = blockIdx.y * 128;
  const int n0 = blockIdx.x * 128;
  const int tid = threadIdx.x;
  const int tm = tid >> 4, tn = tid & 15;
  float acc[8][8] = {};

  const int arow = tid >> 1;
  const int akq  = (tid & 1) * 4;
  const int brow = tid >> 5;
  const int bcol = (tid & 31) * 4;

  for (int k0 = 0; k0 < 512; k0 += 8) {
    float4 av = *(const float4*)&A[(size_t)(m0 + arow) * M_K + k0 + akq];
    float4 bv = *(const float4*)&Bw[(size_t)(k0 + brow) * N + n0 + bcol];
    __syncthreads();
    As[akq + 0][arow] = av.x; As[akq + 1][arow] = av.y;
    As[akq + 2][arow] = av.z; As[akq + 3][arow] = av.w;
    *(float4*)&Bs[brow][bcol] = bv;
    __syncthreads();
#pragma unroll
    for (int kk = 0; kk < 8; ++kk) {
      float a[8], b[8];
      *(float4*)&a[0] = *(const float4*)&As[kk][tm * 8];
      *(float4*)&a[4] = *(const float4*)&As[kk][tm * 8 + 4];
      *(float4*)&b[0] = *(const float4*)&Bs[kk][tn * 8];
      *(float4*)&b[4] = *(const float4*)&Bs[kk][tn * 8 + 4];
#pragma unroll
      for (int i = 0; i < 8; ++i)
#pragma unroll
        for (int j = 0; j < 8; ++j) acc[i][j] = fmaf(a[i], b[j], acc[i][j]);
    }
  }
#pragma unroll
  for (int i = 0; i < 8; ++i) {
    float4* crow = (float4*)&C[(size_t)(m0 + tm * 8 + i) * N + n0 + tn * 8];
    crow[0] = make_float4(acc[i][0], acc[i][1], acc[i][2], acc[i][3]);
    crow[1] = make_float4(acc[i][4], acc[i][5], acc[i][6], acc[i][7]);
  }
}

// ---------------------------------------------------------------------------
// Persistent cooperative scan kernel (structure unchanged from R1; only the
// barrier implementation and the hoisted xp_t load changed).
// ---------------------------------------------------------------------------
__global__ __launch_bounds__(256) void rnn_scan(float* __restrict__ xp,
                                                const float* __restrict__ init_h,
                                                const float* __restrict__ Whh,
                                                const float* __restrict__ bh,
                                                float* __restrict__ h0buf,
                                                float* __restrict__ P,
                                                float* __restrict__ outtail,
                                                unsigned* __restrict__ flags) {
  __shared__ float Wl[128][64];   // 32 KB
  __shared__ float ht[128][34];   // 17 KB
  const int tid = threadIdx.x;
  const int bid = blockIdx.x;
  const int kg = bid & 7;
  const int jg = (bid >> 3) & 15;
  const int bg = bid >> 7;
  const int k0 = kg << 7, j0 = jg << 6, b0 = bg << 5;

  {  // stage W_hh slice (once)
    const int jr = (tid & 15) * 4;
    const int kr = tid >> 4;
#pragma unroll
    for (int p = 0; p < 8; ++p) {
      const int kk = kr + p * 16;
      *(float4*)&Wl[kk][jr] =
          *(const float4*)&Whh[(size_t)(k0 + kk) * 1024 + j0 + jr];
    }
  }

  const int tb = tid >> 4;        // 0..15 : b pair
  const int tj = tid & 15;        // 0..15 : j quad
  const int sb = tid >> 5;        // 0..7  : staging row
  const int sk = (tid & 31) * 4;  // staging k quad
  const int e  = (bid << 8) + tid;  // phase-B element 0..65535
  const int eb = e >> 10;
  const int ej = e & 1023;
  const float bhj = bh[ej];

  for (int t = 0; t < 512; ++t) {
    // ---- phase A ----
    const float* hs;
    size_t rstride;
    if (t == 0)      { hs = init_h;                      rstride = 1024; }
    else if (t == 1) { hs = h0buf;                       rstride = 1024; }
    else             { hs = xp + (size_t)(t - 2) * 1024; rstride = 512 * 1024; }
    __syncthreads();  // previous phase-B done before ht overwrite
#pragma unroll
    for (int p = 0; p < 4; ++p) {
      const int bb = sb + (p << 3);
      float4 hv = *(const float4*)&hs[(size_t)(b0 + bb) * rstride + k0 + sk];
      ht[sk + 0][bb] = hv.x; ht[sk + 1][bb] = hv.y;
      ht[sk + 2][bb] = hv.z; ht[sk + 3][bb] = hv.w;
    }
    // hoist the phase-B xp_t read: slot t is untouched until step t+1, and
    // the load latency hides under the rest of phase A + barrier 1.
    const float xv = xp[((size_t)eb * 512 + t) * 1024 + ej] + bhj;
    __syncthreads();

    float4 acc0 = {0.f, 0.f, 0.f, 0.f};
    float4 acc1 = {0.f, 0.f, 0.f, 0.f};
#pragma unroll 8
    for (int kk = 0; kk < 128; ++kk) {
      const float2 hb = *(const float2*)&ht[kk][tb * 2];
      const float4 w  = *(const float4*)&Wl[kk][tj * 4];
      acc0.x = fmaf(hb.x, w.x, acc0.x); acc0.y = fmaf(hb.x, w.y, acc0.y);
      acc0.z = fmaf(hb.x, w.z, acc0.z); acc0.w = fmaf(hb.x, w.w, acc0.w);
      acc1.x = fmaf(hb.y, w.x, acc1.x); acc1.y = fmaf(hb.y, w.y, acc1.y);
      acc1.z = fmaf(hb.y, w.z, acc1.z); acc1.w = fmaf(hb.y, w.w, acc1.w);
    }
    {
      const size_t base = ((size_t)(kg * 64) + b0 + tb * 2) * 1024 + j0 + tj * 4;
      *(float4*)&P[base]        = acc0;
      *(float4*)&P[base + 1024] = acc1;
    }
    grid_bar(flags, 2 * t + 1);

    // ---- phase B ----
    float ps[8];
#pragma unroll
    for (int g = 0; g < 8; ++g)
      ps[g] = P[((size_t)(g * 64) + eb) * 1024 + ej];
    float v = xv;
#pragma unroll
    for (int g = 0; g < 8; ++g) v += ps[g];
    const float h = tanhf(v);
    if (t == 0) h0buf[e] = h;
    else        xp[((size_t)eb * 512 + (t - 1)) * 1024 + ej] = h;
    if (t == 511) outtail[e] = h;
    if (t != 511) grid_bar(flags, 2 * t + 2);  // kernel end covers the last one
  }
}

// ---------------------------------------------------------------------------
// GEMM3: out[b,t,:] = h_t @ W_hy + b_y;  M=32768 rows (b*512+t), K=1024, N=512
// ---------------------------------------------------------------------------
__global__ __launch_bounds__(256) void gemm_hy(const float* __restrict__ hall,
                                               const float* __restrict__ h0,
                                               const float* __restrict__ Wm,
                                               const float* __restrict__ by,
                                               float* __restrict__ out) {
  const int N = 512;
  __shared__ float As[8][128];
  __shared__ float Bs[8][128];
  const int m0 = blockIdx.y * 128;
  const int n0 = blockIdx.x * 128;
  const int tid = threadIdx.x;
  const int tm = tid >> 4, tn = tid & 15;
  float acc[8][8] = {};

  const int arow = tid >> 1;
  const int akq  = (tid & 1) * 4;
  const int brow = tid >> 5;
  const int bcol = (tid & 31) * 4;

  const int row = m0 + arow;
  const int bb = row >> 9;
  const int tt = row & 511;
  const float* abase = (tt == 0)
      ? (h0 + (size_t)bb * 1024)
      : (hall + ((size_t)bb * 512 + (tt - 1)) * 1024);

  for (int k0 = 0; k0 < 1024; k0 += 8) {
    float4 av = *(const float4*)&abase[k0 + akq];
    float4 bv = *(const float4*)&Wm[(size_t)(k0 + brow) * N + n0 + bcol];
    __syncthreads();
    As[akq + 0][arow] = av.x; As[akq + 1][arow] = av.y;
    As[akq + 2][arow] = av.z; As[akq + 3][arow] = av.w;
    *(float4*)&Bs[brow][bcol] = bv;
    __syncthreads();
#pragma unroll
    for (int kk = 0; kk < 8; ++kk) {
      float a[8], b[8];
      *(float4*)&a[0] = *(const float4*)&As[kk][tm * 8];
      *(float4*)&a[4] = *(const float4*)&As[kk][tm * 8 + 4];
      *(float4*)&b[0] = *(const float4*)&Bs[kk][tn * 8];
      *(float4*)&b[4] = *(const float4*)&Bs[kk][tn * 8 + 4];
#pragma unroll
      for (int i = 0; i < 8; ++i)
#pragma unroll
        for (int j = 0; j < 8; ++j) acc[i][j] = fmaf(a[i], b[j], acc[i][j]);
    }
  }
  float byv[8];
  *(float4*)&byv[0] = *(const float4*)&by[n0 + tn * 8];
  *(float4*)&byv[4] = *(const float4*)&by[n0 + tn * 8 + 4];
#pragma unroll
  for (int i = 0; i < 8; ++i) {
    const int r = m0 + tm * 8 + i;
    float4* crow = (float4*)&out[(size_t)r * N + n0 + tn * 8];
    crow[0] = make_float4(acc[i][0] + byv[0], acc[i][1] + byv[1],
                          acc[i][2] + byv[2], acc[i][3] + byv[3]);
    crow[1] = make_float4(acc[i][4] + byv[4], acc[i][5] + byv[5],
                          acc[i][6] + byv[6], acc[i][7] + byv[7]);
  }
}

// ---------------------------------------------------------------------------
extern "C" void kernel_launch(void* const* d_in, const int* in_sizes, int n_in,
                              void* d_out, int out_size, void* d_ws, size_t ws_size,
                              hipStream_t stream) {
  const float* inputs = (const float*)d_in[0];  // [64][512][512]
  const float* init_h = (const float*)d_in[1];  // [64][1024]
  const float* W_xh   = (const float*)d_in[2];  // [512][1024]
  const float* W_hh   = (const float*)d_in[3];  // [1024][1024]
  const float* W_hy   = (const float*)d_in[4];  // [1024][512]
  const float* b_h    = (const float*)d_in[5];  // [1024]
  const float* b_y    = (const float*)d_in[6];  // [512]
  float* out = (float*)d_out;                   // [64][512][512] ++ [64][1024]

  // Workspace layout (floats):
  //   xp    : 64*512*1024  (x_proj, overwritten in place by h_t at slot t-1)
  //   h0buf : 64*1024
  //   P     : 8*64*1024
  //   flags : NBLK unsigned (must be zeroed every call; ws is poisoned 0xAA)
  float* xp    = (float*)d_ws;
  float* h0buf = xp + (size_t)64 * 512 * 1024;
  float* P     = h0buf + (size_t)64 * 1024;
  unsigned* flags = (unsigned*)(P + (size_t)8 * 64 * 1024);

  hipMemsetAsync(flags, 0, NBLK * sizeof(unsigned), stream);

  gemm_xh<<<dim3(8, 256), 256, 0, stream>>>(inputs, W_xh, xp);

  float* outtail = out + (size_t)64 * 512 * 512;
  void* args[] = { (void*)&xp, (void*)&init_h, (void*)&W_hh, (void*)&b_h,
                   (void*)&h0buf, (void*)&P, (void*)&outtail, (void*)&flags };
  hipLaunchCooperativeKernel((const void*)rnn_scan, dim3(NBLK), dim3(256),
                             args, 0, stream);

  gemm_hy<<<dim3(4, 256), 256, 0, stream>>>(xp, h0buf, W_hy, b_y, out);
}

// Round 4
// 8106.760 us; speedup vs baseline: 3.6332x; 2.5715x over previous
//
#include <hip/hip_runtime.h>
#include <math.h>

// Problem dims (fixed)
//  B=64, T=512, I=512, H=1024, O=512
#define NBLK 256

// ---------------------------------------------------------------------------
// Fine-grained device-coherent (agent-scope, sc1) access helpers.
// These bypass the non-coherent per-XCD caches and are served at the
// coherent point — no bulk wbl2/inv fences needed anywhere.
// ---------------------------------------------------------------------------
__device__ __forceinline__ void st_cg(float* p, float v) {
  __hip_atomic_store(p, v, __ATOMIC_RELAXED, __HIP_MEMORY_SCOPE_AGENT);
}
__device__ __forceinline__ float ld_cg(const float* p) {
  return __hip_atomic_load(p, __ATOMIC_RELAXED, __HIP_MEMORY_SCOPE_AGENT);
}
__device__ __forceinline__ void st2_cg(float* p, float a, float b) {
  unsigned long long u =
      ((unsigned long long)__float_as_uint(b) << 32) | __float_as_uint(a);
  __hip_atomic_store((unsigned long long*)p, u, __ATOMIC_RELAXED,
                     __HIP_MEMORY_SCOPE_AGENT);
}
__device__ __forceinline__ float2 ld2_cg(const float* p) {
  unsigned long long u = __hip_atomic_load(
      (const unsigned long long*)p, __ATOMIC_RELAXED, __HIP_MEMORY_SCOPE_AGENT);
  float2 r;
  r.x = __uint_as_float((unsigned)u);
  r.y = __uint_as_float((unsigned)(u >> 32));
  return r;
}

// ---------------------------------------------------------------------------
// Fence-free grid barrier (monotonic flags, one per block).
//  - all cross-block data is written with sc1 stores; every wave drains its
//    own vmcnt before s_barrier, so data is at the coherent point before
//    thread 0 publishes the flag (also sc1).
//  - poll: relaxed agent loads (proven coherent cross-XCD in R3).
//  - NO buffer_wbl2 / buffer_inv — that tag-walk pair was ~16-20 us/step.
// ---------------------------------------------------------------------------
__device__ __forceinline__ void grid_bar(unsigned* flags, unsigned target) {
  asm volatile("s_waitcnt vmcnt(0)" ::: "memory");  // this wave's sc1 stores
  __syncthreads();  // all waves drained (compiler adds waitcnt pre-barrier)
  if (threadIdx.x == 0) {
    __hip_atomic_store(&flags[blockIdx.x], target, __ATOMIC_RELAXED,
                       __HIP_MEMORY_SCOPE_AGENT);
  }
  while (__hip_atomic_load(&flags[threadIdx.x], __ATOMIC_RELAXED,
                           __HIP_MEMORY_SCOPE_AGENT) < target) {
    __builtin_amdgcn_s_sleep(2);
  }
  __syncthreads();  // whole block has observed all 256 flags
  asm volatile("" ::: "memory");  // keep data reads below the barrier
}

// ---------------------------------------------------------------------------
// GEMM1: xp[m][n] = inputs[m][k] * W_xh[k][n];  M=32768, K=512, N=1024
// ---------------------------------------------------------------------------
__global__ __launch_bounds__(256) void gemm_xh(const float* __restrict__ A,
                                               const float* __restrict__ Bw,
                                               float* __restrict__ C) {
  const int M_K = 512;
  const int N = 1024;
  __shared__ float As[8][128];
  __shared__ float Bs[8][128];
  const int m0 = blockIdx.y * 128;
  const int n0 = blockIdx.x * 128;
  const int tid = threadIdx.x;
  const int tm = tid >> 4, tn = tid & 15;
  float acc[8][8] = {};

  const int arow = tid >> 1;
  const int akq  = (tid & 1) * 4;
  const int brow = tid >> 5;
  const int bcol = (tid & 31) * 4;

  for (int k0 = 0; k0 < 512; k0 += 8) {
    float4 av = *(const float4*)&A[(size_t)(m0 + arow) * M_K + k0 + akq];
    float4 bv = *(const float4*)&Bw[(size_t)(k0 + brow) * N + n0 + bcol];
    __syncthreads();
    As[akq + 0][arow] = av.x; As[akq + 1][arow] = av.y;
    As[akq + 2][arow] = av.z; As[akq + 3][arow] = av.w;
    *(float4*)&Bs[brow][bcol] = bv;
    __syncthreads();
#pragma unroll
    for (int kk = 0; kk < 8; ++kk) {
      float a[8], b[8];
      *(float4*)&a[0] = *(const float4*)&As[kk][tm * 8];
      *(float4*)&a[4] = *(const float4*)&As[kk][tm * 8 + 4];
      *(float4*)&b[0] = *(const float4*)&Bs[kk][tn * 8];
      *(float4*)&b[4] = *(const float4*)&Bs[kk][tn * 8 + 4];
#pragma unroll
      for (int i = 0; i < 8; ++i)
#pragma unroll
        for (int j = 0; j < 8; ++j) acc[i][j] = fmaf(a[i], b[j], acc[i][j]);
    }
  }
#pragma unroll
  for (int i = 0; i < 8; ++i) {
    float4* crow = (float4*)&C[(size_t)(m0 + tm * 8 + i) * N + n0 + tn * 8];
    crow[0] = make_float4(acc[i][0], acc[i][1], acc[i][2], acc[i][3]);
    crow[1] = make_float4(acc[i][4], acc[i][5], acc[i][6], acc[i][7]);
  }
}

// ---------------------------------------------------------------------------
// Persistent cooperative scan kernel. Structure = R3; all cross-block data
// (h staging loads, P partials both ways, h writes) now use sc1 accesses,
// and the barrier carries no cache-maintenance fences.
// ---------------------------------------------------------------------------
__global__ __launch_bounds__(256) void rnn_scan(float* __restrict__ xp,
                                                const float* __restrict__ init_h,
                                                const float* __restrict__ Whh,
                                                const float* __restrict__ bh,
                                                float* __restrict__ h0buf,
                                                float* __restrict__ P,
                                                float* __restrict__ outtail,
                                                unsigned* __restrict__ flags) {
  __shared__ float Wl[128][64];   // 32 KB
  __shared__ float ht[128][34];   // 17 KB
  const int tid = threadIdx.x;
  const int bid = blockIdx.x;
  const int kg = bid & 7;
  const int jg = (bid >> 3) & 15;
  const int bg = bid >> 7;
  const int k0 = kg << 7, j0 = jg << 6, b0 = bg << 5;

  {  // stage W_hh slice (once; read-only, normal cached loads)
    const int jr = (tid & 15) * 4;
    const int kr = tid >> 4;
#pragma unroll
    for (int p = 0; p < 8; ++p) {
      const int kk = kr + p * 16;
      *(float4*)&Wl[kk][jr] =
          *(const float4*)&Whh[(size_t)(k0 + kk) * 1024 + j0 + jr];
    }
  }

  const int tb = tid >> 4;        // 0..15 : b pair
  const int tj = tid & 15;        // 0..15 : j quad
  const int sb = tid >> 5;        // 0..7  : staging row
  const int sk = (tid & 31) * 4;  // staging k quad
  const int e  = (bid << 8) + tid;  // phase-B element 0..65535
  const int eb = e >> 10;
  const int ej = e & 1023;
  const float bhj = bh[ej];

  for (int t = 0; t < 512; ++t) {
    // ---- phase A ----
    const float* hs;
    size_t rstride;
    if (t == 0)      { hs = init_h;                      rstride = 1024; }
    else if (t == 1) { hs = h0buf;                       rstride = 1024; }
    else             { hs = xp + (size_t)(t - 2) * 1024; rstride = 512 * 1024; }
    __syncthreads();  // previous phase-B done before ht overwrite
#pragma unroll
    for (int p = 0; p < 4; ++p) {
      const int bb = sb + (p << 3);
      const float* src = &hs[(size_t)(b0 + bb) * rstride + k0 + sk];
      float2 lo = ld2_cg(src);      // sc1: coherent read of cross-block h
      float2 hi = ld2_cg(src + 2);
      ht[sk + 0][bb] = lo.x; ht[sk + 1][bb] = lo.y;
      ht[sk + 2][bb] = hi.x; ht[sk + 3][bb] = hi.y;
    }
    // hoisted phase-B xp_t read: slot t untouched until step t+1 phase B,
    // and only this block's XCD ever caches it pre-overwrite (coherent).
    const float xv = xp[((size_t)eb * 512 + t) * 1024 + ej] + bhj;
    __syncthreads();

    float4 acc0 = {0.f, 0.f, 0.f, 0.f};
    float4 acc1 = {0.f, 0.f, 0.f, 0.f};
#pragma unroll 8
    for (int kk = 0; kk < 128; ++kk) {
      const float2 hb = *(const float2*)&ht[kk][tb * 2];
      const float4 w  = *(const float4*)&Wl[kk][tj * 4];
      acc0.x = fmaf(hb.x, w.x, acc0.x); acc0.y = fmaf(hb.x, w.y, acc0.y);
      acc0.z = fmaf(hb.x, w.z, acc0.z); acc0.w = fmaf(hb.x, w.w, acc0.w);
      acc1.x = fmaf(hb.y, w.x, acc1.x); acc1.y = fmaf(hb.y, w.y, acc1.y);
      acc1.z = fmaf(hb.y, w.z, acc1.z); acc1.w = fmaf(hb.y, w.w, acc1.w);
    }
    {
      const size_t base = ((size_t)(kg * 64) + b0 + tb * 2) * 1024 + j0 + tj * 4;
      st2_cg(&P[base + 0], acc0.x, acc0.y);
      st2_cg(&P[base + 2], acc0.z, acc0.w);
      st2_cg(&P[base + 1024], acc1.x, acc1.y);
      st2_cg(&P[base + 1026], acc1.z, acc1.w);
    }
    grid_bar(flags, 2 * t + 1);

    // ---- phase B ----
    float ps[8];
#pragma unroll
    for (int g = 0; g < 8; ++g)
      ps[g] = ld_cg(&P[((size_t)(g * 64) + eb) * 1024 + ej]);
    float v = xv;
#pragma unroll
    for (int g = 0; g < 8; ++g) v += ps[g];
    const float h = tanhf(v);
    if (t == 0) st_cg(&h0buf[e], h);
    else        st_cg(&xp[((size_t)eb * 512 + (t - 1)) * 1024 + ej], h);
    if (t == 511) outtail[e] = h;  // normal store; kernel-end flush covers it
    if (t != 511) grid_bar(flags, 2 * t + 2);  // kernel end covers the last one
  }
}

// ---------------------------------------------------------------------------
// GEMM3: out[b,t,:] = h_t @ W_hy + b_y;  M=32768 rows (b*512+t), K=1024, N=512
// (separate dispatch: CP kernel-boundary flush/inv makes sc1-written h
//  visible to normal cached loads here)
// ---------------------------------------------------------------------------
__global__ __launch_bounds__(256) void gemm_hy(const float* __restrict__ hall,
                                               const float* __restrict__ h0,
                                               const float* __restrict__ Wm,
                                               const float* __restrict__ by,
                                               float* __restrict__ out) {
  const int N = 512;
  __shared__ float As[8][128];
  __shared__ float Bs[8][128];
  const int m0 = blockIdx.y * 128;
  const int n0 = blockIdx.x * 128;
  const int tid = threadIdx.x;
  const int tm = tid >> 4, tn = tid & 15;
  float acc[8][8] = {};

  const int arow = tid >> 1;
  const int akq  = (tid & 1) * 4;
  const int brow = tid >> 5;
  const int bcol = (tid & 31) * 4;

  const int row = m0 + arow;
  const int bb = row >> 9;
  const int tt = row & 511;
  const float* abase = (tt == 0)
      ? (h0 + (size_t)bb * 1024)
      : (hall + ((size_t)bb * 512 + (tt - 1)) * 1024);

  for (int k0 = 0; k0 < 1024; k0 += 8) {
    float4 av = *(const float4*)&abase[k0 + akq];
    float4 bv = *(const float4*)&Wm[(size_t)(k0 + brow) * N + n0 + bcol];
    __syncthreads();
    As[akq + 0][arow] = av.x; As[akq + 1][arow] = av.y;
    As[akq + 2][arow] = av.z; As[akq + 3][arow] = av.w;
    *(float4*)&Bs[brow][bcol] = bv;
    __syncthreads();
#pragma unroll
    for (int kk = 0; kk < 8; ++kk) {
      float a[8], b[8];
      *(float4*)&a[0] = *(const float4*)&As[kk][tm * 8];
      *(float4*)&a[4] = *(const float4*)&As[kk][tm * 8 + 4];
      *(float4*)&b[0] = *(const float4*)&Bs[kk][tn * 8];
      *(float4*)&b[4] = *(const float4*)&Bs[kk][tn * 8 + 4];
#pragma unroll
      for (int i = 0; i < 8; ++i)
#pragma unroll
        for (int j = 0; j < 8; ++j) acc[i][j] = fmaf(a[i], b[j], acc[i][j]);
    }
  }
  float byv[8];
  *(float4*)&byv[0] = *(const float4*)&by[n0 + tn * 8];
  *(float4*)&byv[4] = *(const float4*)&by[n0 + tn * 8 + 4];
#pragma unroll
  for (int i = 0; i < 8; ++i) {
    const int r = m0 + tm * 8 + i;
    float4* crow = (float4*)&out[(size_t)r * N + n0 + tn * 8];
    crow[0] = make_float4(acc[i][0] + byv[0], acc[i][1] + byv[1],
                          acc[i][2] + byv[2], acc[i][3] + byv[3]);
    crow[1] = make_float4(acc[i][4] + byv[4], acc[i][5] + byv[5],
                          acc[i][6] + byv[6], acc[i][7] + byv[7]);
  }
}

// ---------------------------------------------------------------------------
extern "C" void kernel_launch(void* const* d_in, const int* in_sizes, int n_in,
                              void* d_out, int out_size, void* d_ws, size_t ws_size,
                              hipStream_t stream) {
  const float* inputs = (const float*)d_in[0];  // [64][512][512]
  const float* init_h = (const float*)d_in[1];  // [64][1024]
  const float* W_xh   = (const float*)d_in[2];  // [512][1024]
  const float* W_hh   = (const float*)d_in[3];  // [1024][1024]
  const float* W_hy   = (const float*)d_in[4];  // [1024][512]
  const float* b_h    = (const float*)d_in[5];  // [1024]
  const float* b_y    = (const float*)d_in[6];  // [512]
  float* out = (float*)d_out;                   // [64][512][512] ++ [64][1024]

  // Workspace layout (floats):
  //   xp    : 64*512*1024  (x_proj, overwritten in place by h_t at slot t-1)
  //   h0buf : 64*1024
  //   P     : 8*64*1024
  //   flags : NBLK unsigned (zeroed every call; ws is re-poisoned 0xAA)
  float* xp    = (float*)d_ws;
  float* h0buf = xp + (size_t)64 * 512 * 1024;
  float* P     = h0buf + (size_t)64 * 1024;
  unsigned* flags = (unsigned*)(P + (size_t)8 * 64 * 1024);

  hipMemsetAsync(flags, 0, NBLK * sizeof(unsigned), stream);

  gemm_xh<<<dim3(8, 256), 256, 0, stream>>>(inputs, W_xh, xp);

  float* outtail = out + (size_t)64 * 512 * 512;
  void* args[] = { (void*)&xp, (void*)&init_h, (void*)&W_hh, (void*)&b_h,
                   (void*)&h0buf, (void*)&P, (void*)&outtail, (void*)&flags };
  hipLaunchCooperativeKernel((const void*)rnn_scan, dim3(NBLK), dim3(256),
                             args, 0, stream);

  gemm_hy<<<dim3(4, 256), 256, 0, stream>>>(xp, h0buf, W_hy, b_y, out);
}

// Round 6
// 5293.062 us; speedup vs baseline: 5.5645x; 1.5316x over previous
//
#include <hip/hip_runtime.h>
#include <math.h>

// Problem dims (fixed)
//  B=64, T=512, I=512, H=1024, O=512
#define NBLK 256
#define FLAG_STRIDE 32  // unsigneds; pads each block's flag to its own 128B line

// clang ext-vector: maps to a direct 4-VGPR tuple (legal inline-asm operand,
// unlike HIP's struct float4 which is indirectly passed).
typedef float f32x4 __attribute__((ext_vector_type(4)));

// ---------------------------------------------------------------------------
// Fine-grained device-coherent (sc0 sc1) 16B access helpers, inline asm.
// Loads are issued without waits; the join asm ties the results via "+v" so
// consumers cannot be scheduled above the s_waitcnt (guide rule #18).
// ---------------------------------------------------------------------------
__device__ __forceinline__ f32x4 ld4_cg_issue(const float* p) {
  f32x4 r;
  asm volatile("global_load_dwordx4 %0, %1, off sc0 sc1"
               : "=v"(r) : "v"(p));
  return r;
}
__device__ __forceinline__ void st4_cg(float* p, f32x4 v) {
  asm volatile("global_store_dwordx4 %0, %1, off sc0 sc1"
               :: "v"(p), "v"(v) : "memory");
}

// ---------------------------------------------------------------------------
// Tree grid barrier (epoch-based, hotspot-free).
//  - publishers: thread 0 of each block -> flags[bid*FLAG_STRIDE] (own line)
//  - aggregator: block 0, one thread per block-flag (256 tx/round, 256 lines)
//  - broadcast: single epoch word; ONE thread per block polls it
//  - all values monotonic; stale reads only over-spin.
// ---------------------------------------------------------------------------
__device__ __forceinline__ void grid_bar(unsigned* flags, unsigned* epoch,
                                         unsigned target) {
  asm volatile("s_waitcnt vmcnt(0)" ::: "memory");  // drain this wave's sc1 stores
  __syncthreads();                                  // all waves drained
  if (threadIdx.x == 0) {
    __hip_atomic_store(&flags[blockIdx.x * FLAG_STRIDE], target,
                       __ATOMIC_RELAXED, __HIP_MEMORY_SCOPE_AGENT);
  }
  if (blockIdx.x == 0) {
    while (__hip_atomic_load(&flags[threadIdx.x * FLAG_STRIDE],
                             __ATOMIC_RELAXED, __HIP_MEMORY_SCOPE_AGENT) <
           target) {
      __builtin_amdgcn_s_sleep(2);
    }
    __syncthreads();  // block 0 has observed all 256 flags
    if (threadIdx.x == 0) {
      __hip_atomic_store(epoch, target, __ATOMIC_RELAXED,
                         __HIP_MEMORY_SCOPE_AGENT);
    }
  } else {
    if (threadIdx.x == 0) {
      while (__hip_atomic_load(epoch, __ATOMIC_RELAXED,
                               __HIP_MEMORY_SCOPE_AGENT) < target) {
        __builtin_amdgcn_s_sleep(2);
      }
    }
    __syncthreads();  // releases the block once thread 0 saw the epoch
  }
  asm volatile("" ::: "memory");
}

// ---------------------------------------------------------------------------
// GEMM1: xp[m][n] = inputs[m][k] * W_xh[k][n];  M=32768, K=512, N=1024
// ---------------------------------------------------------------------------
__global__ __launch_bounds__(256) void gemm_xh(const float* __restrict__ A,
                                               const float* __restrict__ Bw,
                                               float* __restrict__ C) {
  const int M_K = 512;
  const int N = 1024;
  __shared__ float As[8][128];
  __shared__ float Bs[8][128];
  const int m0 = blockIdx.y * 128;
  const int n0 = blockIdx.x * 128;
  const int tid = threadIdx.x;
  const int tm = tid >> 4, tn = tid & 15;
  float acc[8][8] = {};

  const int arow = tid >> 1;
  const int akq  = (tid & 1) * 4;
  const int brow = tid >> 5;
  const int bcol = (tid & 31) * 4;

  for (int k0 = 0; k0 < 512; k0 += 8) {
    float4 av = *(const float4*)&A[(size_t)(m0 + arow) * M_K + k0 + akq];
    float4 bv = *(const float4*)&Bw[(size_t)(k0 + brow) * N + n0 + bcol];
    __syncthreads();
    As[akq + 0][arow] = av.x; As[akq + 1][arow] = av.y;
    As[akq + 2][arow] = av.z; As[akq + 3][arow] = av.w;
    *(float4*)&Bs[brow][bcol] = bv;
    __syncthreads();
#pragma unroll
    for (int kk = 0; kk < 8; ++kk) {
      float a[8], b[8];
      *(float4*)&a[0] = *(const float4*)&As[kk][tm * 8];
      *(float4*)&a[4] = *(const float4*)&As[kk][tm * 8 + 4];
      *(float4*)&b[0] = *(const float4*)&Bs[kk][tn * 8];
      *(float4*)&b[4] = *(const float4*)&Bs[kk][tn * 8 + 4];
#pragma unroll
      for (int i = 0; i < 8; ++i)
#pragma unroll
        for (int j = 0; j < 8; ++j) acc[i][j] = fmaf(a[i], b[j], acc[i][j]);
    }
  }
#pragma unroll
  for (int i = 0; i < 8; ++i) {
    float4* crow = (float4*)&C[(size_t)(m0 + tm * 8 + i) * N + n0 + tn * 8];
    crow[0] = make_float4(acc[i][0], acc[i][1], acc[i][2], acc[i][3]);
    crow[1] = make_float4(acc[i][4], acc[i][5], acc[i][6], acc[i][7]);
  }
}

// ---------------------------------------------------------------------------
// Persistent cooperative scan kernel.
// Decomposition unchanged (kg8 x jg16 x bg2). Changes vs R4:
//  - all cross-block sc1 data traffic is 16B (dwordx4)
//  - phase B done by wave 0 only, 4 j-consecutive elements per thread
//  - tree barrier (flags padded, epoch broadcast)
// ---------------------------------------------------------------------------
__global__ __launch_bounds__(256) void rnn_scan(float* __restrict__ xp,
                                                const float* __restrict__ init_h,
                                                const float* __restrict__ Whh,
                                                const float* __restrict__ bh,
                                                float* __restrict__ h0buf,
                                                float* __restrict__ P,
                                                float* __restrict__ outtail,
                                                unsigned* __restrict__ flags,
                                                unsigned* __restrict__ epoch) {
  __shared__ float Wl[128][64];   // 32 KB
  __shared__ float ht[128][34];   // 17 KB
  const int tid = threadIdx.x;
  const int bid = blockIdx.x;
  const int kg = bid & 7;
  const int jg = (bid >> 3) & 15;
  const int bg = bid >> 7;
  const int k0 = kg << 7, j0 = jg << 6, b0 = bg << 5;

  {  // stage W_hh slice (once; read-only, normal cached loads)
    const int jr = (tid & 15) * 4;
    const int kr = tid >> 4;
#pragma unroll
    for (int p = 0; p < 8; ++p) {
      const int kk = kr + p * 16;
      *(float4*)&Wl[kk][jr] =
          *(const float4*)&Whh[(size_t)(k0 + kk) * 1024 + j0 + jr];
    }
  }

  const int tb = tid >> 4;        // 0..15 : b pair (inner-loop output rows)
  const int tj = tid & 15;        // 0..15 : j quad
  const int sb = tid >> 5;        // 0..7  : staging row
  const int sk = (tid & 31) * 4;  // staging k quad
  // phase-B mapping (wave 0 only): quad q -> elements e4..e4+3
  const int q  = (bid << 6) + tid;   // valid for tid<64
  const int e4 = q << 2;
  const int qb = e4 >> 10;           // batch row
  const int qj = e4 & 1023;          // j (16B aligned)
  f32x4 bh4 = 0.f;
  if (tid < 64) bh4 = *(const f32x4*)&bh[qj];

  for (int t = 0; t < 512; ++t) {
    // ---- phase A ----
    const float* hs;
    size_t rstride;
    if (t == 0)      { hs = init_h;                      rstride = 1024; }
    else if (t == 1) { hs = h0buf;                       rstride = 1024; }
    else             { hs = xp + (size_t)(t - 2) * 1024; rstride = 512 * 1024; }
    __syncthreads();  // previous phase done before ht overwrite
    f32x4 hv0 = ld4_cg_issue(&hs[(size_t)(b0 + sb +  0) * rstride + k0 + sk]);
    f32x4 hv1 = ld4_cg_issue(&hs[(size_t)(b0 + sb +  8) * rstride + k0 + sk]);
    f32x4 hv2 = ld4_cg_issue(&hs[(size_t)(b0 + sb + 16) * rstride + k0 + sk]);
    f32x4 hv3 = ld4_cg_issue(&hs[(size_t)(b0 + sb + 24) * rstride + k0 + sk]);
    // hoisted phase-B xp_t read (wave 0): slot t untouched until step t+1.
    f32x4 xv4 = 0.f;
    if (tid < 64)
      xv4 = *(const f32x4*)&xp[((size_t)qb * 512 + t) * 1024 + qj];
    asm volatile("s_waitcnt vmcnt(0)"
                 : "+v"(hv0), "+v"(hv1), "+v"(hv2), "+v"(hv3) :: "memory");
    ht[sk + 0][sb +  0] = hv0.x; ht[sk + 1][sb +  0] = hv0.y;
    ht[sk + 2][sb +  0] = hv0.z; ht[sk + 3][sb +  0] = hv0.w;
    ht[sk + 0][sb +  8] = hv1.x; ht[sk + 1][sb +  8] = hv1.y;
    ht[sk + 2][sb +  8] = hv1.z; ht[sk + 3][sb +  8] = hv1.w;
    ht[sk + 0][sb + 16] = hv2.x; ht[sk + 1][sb + 16] = hv2.y;
    ht[sk + 2][sb + 16] = hv2.z; ht[sk + 3][sb + 16] = hv2.w;
    ht[sk + 0][sb + 24] = hv3.x; ht[sk + 1][sb + 24] = hv3.y;
    ht[sk + 2][sb + 24] = hv3.z; ht[sk + 3][sb + 24] = hv3.w;
    __syncthreads();

    float4 acc0 = {0.f, 0.f, 0.f, 0.f};
    float4 acc1 = {0.f, 0.f, 0.f, 0.f};
#pragma unroll 8
    for (int kk = 0; kk < 128; ++kk) {
      const float2 hb = *(const float2*)&ht[kk][tb * 2];
      const float4 w  = *(const float4*)&Wl[kk][tj * 4];
      acc0.x = fmaf(hb.x, w.x, acc0.x); acc0.y = fmaf(hb.x, w.y, acc0.y);
      acc0.z = fmaf(hb.x, w.z, acc0.z); acc0.w = fmaf(hb.x, w.w, acc0.w);
      acc1.x = fmaf(hb.y, w.x, acc1.x); acc1.y = fmaf(hb.y, w.y, acc1.y);
      acc1.z = fmaf(hb.y, w.z, acc1.z); acc1.w = fmaf(hb.y, w.w, acc1.w);
    }
    {
      const size_t base = ((size_t)(kg * 64) + b0 + tb * 2) * 1024 + j0 + tj * 4;
      f32x4 a0 = {acc0.x, acc0.y, acc0.z, acc0.w};
      f32x4 a1 = {acc1.x, acc1.y, acc1.z, acc1.w};
      st4_cg(&P[base], a0);
      st4_cg(&P[base + 1024], a1);
    }
    grid_bar(flags, epoch, 2 * t + 1);

    // ---- phase B (wave 0 only; 4 j-consecutive elements per thread) ----
    if (tid < 64) {
      f32x4 p0 = ld4_cg_issue(&P[((size_t)(0 * 64) + qb) * 1024 + qj]);
      f32x4 p1 = ld4_cg_issue(&P[((size_t)(1 * 64) + qb) * 1024 + qj]);
      f32x4 p2 = ld4_cg_issue(&P[((size_t)(2 * 64) + qb) * 1024 + qj]);
      f32x4 p3 = ld4_cg_issue(&P[((size_t)(3 * 64) + qb) * 1024 + qj]);
      f32x4 p4 = ld4_cg_issue(&P[((size_t)(4 * 64) + qb) * 1024 + qj]);
      f32x4 p5 = ld4_cg_issue(&P[((size_t)(5 * 64) + qb) * 1024 + qj]);
      f32x4 p6 = ld4_cg_issue(&P[((size_t)(6 * 64) + qb) * 1024 + qj]);
      f32x4 p7 = ld4_cg_issue(&P[((size_t)(7 * 64) + qb) * 1024 + qj]);
      asm volatile("s_waitcnt vmcnt(0)"
                   : "+v"(p0), "+v"(p1), "+v"(p2), "+v"(p3),
                     "+v"(p4), "+v"(p5), "+v"(p6), "+v"(p7) :: "memory");
      f32x4 v = xv4 + bh4 + ((p0 + p1) + (p2 + p3)) + ((p4 + p5) + (p6 + p7));
      f32x4 hq;
      hq.x = tanhf(v.x); hq.y = tanhf(v.y);
      hq.z = tanhf(v.z); hq.w = tanhf(v.w);
      if (t == 0) st4_cg(&h0buf[e4], hq);
      else        st4_cg(&xp[((size_t)qb * 512 + (t - 1)) * 1024 + qj], hq);
      if (t == 511) *(f32x4*)&outtail[e4] = hq;  // normal store; kernel-end flush
    }
    if (t != 511) grid_bar(flags, epoch, 2 * t + 2);
  }
}

// ---------------------------------------------------------------------------
// GEMM3: out[b,t,:] = h_t @ W_hy + b_y;  M=32768 rows (b*512+t), K=1024, N=512
// ---------------------------------------------------------------------------
__global__ __launch_bounds__(256) void gemm_hy(const float* __restrict__ hall,
                                               const float* __restrict__ h0,
                                               const float* __restrict__ Wm,
                                               const float* __restrict__ by,
                                               float* __restrict__ out) {
  const int N = 512;
  __shared__ float As[8][128];
  __shared__ float Bs[8][128];
  const int m0 = blockIdx.y * 128;
  const int n0 = blockIdx.x * 128;
  const int tid = threadIdx.x;
  const int tm = tid >> 4, tn = tid & 15;
  float acc[8][8] = {};

  const int arow = tid >> 1;
  const int akq  = (tid & 1) * 4;
  const int brow = tid >> 5;
  const int bcol = (tid & 31) * 4;

  const int row = m0 + arow;
  const int bb = row >> 9;
  const int tt = row & 511;
  const float* abase = (tt == 0)
      ? (h0 + (size_t)bb * 1024)
      : (hall + ((size_t)bb * 512 + (tt - 1)) * 1024);

  for (int k0 = 0; k0 < 1024; k0 += 8) {
    float4 av = *(const float4*)&abase[k0 + akq];
    float4 bv = *(const float4*)&Wm[(size_t)(k0 + brow) * N + n0 + bcol];
    __syncthreads();
    As[akq + 0][arow] = av.x; As[akq + 1][arow] = av.y;
    As[akq + 2][arow] = av.z; As[akq + 3][arow] = av.w;
    *(float4*)&Bs[brow][bcol] = bv;
    __syncthreads();
#pragma unroll
    for (int kk = 0; kk < 8; ++kk) {
      float a[8], b[8];
      *(float4*)&a[0] = *(const float4*)&As[kk][tm * 8];
      *(float4*)&a[4] = *(const float4*)&As[kk][tm * 8 + 4];
      *(float4*)&b[0] = *(const float4*)&Bs[kk][tn * 8];
      *(float4*)&b[4] = *(const float4*)&Bs[kk][tn * 8 + 4];
#pragma unroll
      for (int i = 0; i < 8; ++i)
#pragma unroll
        for (int j = 0; j < 8; ++j) acc[i][j] = fmaf(a[i], b[j], acc[i][j]);
    }
  }
  float byv[8];
  *(float4*)&byv[0] = *(const float4*)&by[n0 + tn * 8];
  *(float4*)&byv[4] = *(const float4*)&by[n0 + tn * 8 + 4];
#pragma unroll
  for (int i = 0; i < 8; ++i) {
    const int r = m0 + tm * 8 + i;
    float4* crow = (float4*)&out[(size_t)r * N + n0 + tn * 8];
    crow[0] = make_float4(acc[i][0] + byv[0], acc[i][1] + byv[1],
                          acc[i][2] + byv[2], acc[i][3] + byv[3]);
    crow[1] = make_float4(acc[i][4] + byv[4], acc[i][5] + byv[5],
                          acc[i][6] + byv[6], acc[i][7] + byv[7]);
  }
}

// ---------------------------------------------------------------------------
extern "C" void kernel_launch(void* const* d_in, const int* in_sizes, int n_in,
                              void* d_out, int out_size, void* d_ws, size_t ws_size,
                              hipStream_t stream) {
  const float* inputs = (const float*)d_in[0];  // [64][512][512]
  const float* init_h = (const float*)d_in[1];  // [64][1024]
  const float* W_xh   = (const float*)d_in[2];  // [512][1024]
  const float* W_hh   = (const float*)d_in[3];  // [1024][1024]
  const float* W_hy   = (const float*)d_in[4];  // [1024][512]
  const float* b_h    = (const float*)d_in[5];  // [1024]
  const float* b_y    = (const float*)d_in[6];  // [512]
  float* out = (float*)d_out;                   // [64][512][512] ++ [64][1024]

  // Workspace layout (floats):
  //   xp    : 64*512*1024  (x_proj, overwritten in place by h_t at slot t-1)
  //   h0buf : 64*1024
  //   P     : 8*64*1024
  //   flags : NBLK*FLAG_STRIDE unsigned (padded: one line per block) + epoch
  float* xp    = (float*)d_ws;
  float* h0buf = xp + (size_t)64 * 512 * 1024;
  float* P     = h0buf + (size_t)64 * 1024;
  unsigned* flags = (unsigned*)(P + (size_t)8 * 64 * 1024);
  unsigned* epoch = flags + (size_t)NBLK * FLAG_STRIDE;

  hipMemsetAsync(flags, 0, (NBLK * FLAG_STRIDE + 32) * sizeof(unsigned), stream);

  gemm_xh<<<dim3(8, 256), 256, 0, stream>>>(inputs, W_xh, xp);

  float* outtail = out + (size_t)64 * 512 * 512;
  void* args[] = { (void*)&xp, (void*)&init_h, (void*)&W_hh, (void*)&b_h,
                   (void*)&h0buf, (void*)&P, (void*)&outtail, (void*)&flags,
                   (void*)&epoch };
  hipLaunchCooperativeKernel((const void*)rnn_scan, dim3(NBLK), dim3(256),
                             args, 0, stream);

  gemm_hy<<<dim3(4, 256), 256, 0, stream>>>(xp, h0buf, W_hy, b_y, out);
}